// Round 1
// baseline (1092.004 us; speedup 1.0000x reference)
//
#include <hip/hip_runtime.h>
#include <math.h>

#define N_NODES   100000
#define N_EDGES   200000
#define NNZ       2000000
#define DD        64
#define HH        32
#define K_KEEP    1000000

// ---------------- workspace layout (bytes) ----------------
// p_a      f64 [N_NODES*32]   @ 0            25,600,000
// p_b      f64 [N_NODES*32]   @ 25,600,000   25,600,000
// probs64  f64 [NNZ]          @ 51,200,000   16,000,000
// --- zero region start ---
// edge_acc f64 [N_EDGES*32]   @ 67,200,000   51,200,000
// eprob    f64 [N_EDGES]      @ 118,400,000   1,600,000
// edge_cnt u32 [N_EDGES]      @ 120,000,000     800,000
// hard_cnt u32 [N_EDGES]      @ 120,800,000     800,000
// histv    u32 [8*256]        @ 121,600,000       8,192
// histi    u32 [3*128]        @ 121,608,192       1,536
// state                       @ 121,609,728          64
// --- zero region end: 121,609,792 total ---
#define OFF_PA    ((size_t)0)
#define OFF_PB    ((size_t)25600000)
#define OFF_P64   ((size_t)51200000)
#define OFF_EACC  ((size_t)67200000)
#define OFF_EPR   ((size_t)118400000)
#define OFF_ECNT  ((size_t)120000000)
#define OFF_HCNT  ((size_t)120800000)
#define OFF_HV    ((size_t)121600000)
#define OFF_HI    ((size_t)121608192)
#define OFF_ST    ((size_t)121609728)
#define ZERO_OFF  OFF_EACC
#define ZERO_LEN  ((size_t)(121609792 - 67200000))

struct SelState {
    unsigned long long prefix;     // value-select key prefix (f64 bits of T)
    unsigned int kk;               // remaining descending rank
    unsigned int rr;               // remaining ascending rank among equals
    unsigned int idx_prefix;       // index-select prefix
    unsigned int idx_thresh;       // final: index of r-th smallest equal
};

__global__ void init_kernel(SelState* st) {
    if (threadIdx.x == 0) {
        st->prefix = 0ull;
        st->kk = K_KEEP;
        st->rr = 0;
        st->idx_prefix = 0;
        st->idx_thresh = 0;
    }
}

// p_a[v][k] = sum_d x[v][d] * W1[d][k]; p_b[v][k] = sum_d x[v][d] * W1[64+d][k]
__global__ void proj_kernel(const float* __restrict__ x, const float* __restrict__ W1,
                            double* __restrict__ p_a, double* __restrict__ p_b) {
    __shared__ float sW[128 * 32];   // 16 KB
    __shared__ float sx[8][64];      // 2 KB
    for (int t = threadIdx.x; t < 128 * 32; t += 256) sW[t] = W1[t];
    int base = blockIdx.x * 8;
    for (int t = threadIdx.x; t < 512; t += 256) {
        int n = t >> 6, d = t & 63;
        int g = base + n;
        sx[n][d] = (g < N_NODES) ? x[(size_t)g * DD + d] : 0.f;
    }
    __syncthreads();
    int ln = threadIdx.x >> 5;
    int k  = threadIdx.x & 31;
    int node = base + ln;
    if (node >= N_NODES) return;
    double sa = 0.0, sb = 0.0;
    for (int d = 0; d < 64; ++d) {
        double xv = (double)sx[ln][d];
        sa += xv * (double)sW[d * 32 + k];
        sb += xv * (double)sW[(64 + d) * 32 + k];
    }
    p_a[(size_t)node * 32 + k] = sa;
    p_b[(size_t)node * 32 + k] = sb;
}

// half-wave (32 lanes) per incidence: edge_acc[e][k] += p_b[v][k]; edge_cnt[e]++
__global__ void scatter_kernel(const int* __restrict__ V, const int* __restrict__ E,
                               const double* __restrict__ p_b,
                               double* __restrict__ edge_acc, unsigned int* __restrict__ edge_cnt) {
    int j = blockIdx.x * 8 + (threadIdx.x >> 5);
    if (j >= NNZ) return;
    int k = threadIdx.x & 31;
    int v = V[j], e = E[j];
    unsafeAtomicAdd(&edge_acc[(size_t)e * 32 + k], p_b[(size_t)v * 32 + k]);
    if (k == 0) atomicAdd(&edge_cnt[e], 1u);
}

// edge_acc[e][k] /= max(cnt[e],1)
__global__ void edge_mean_kernel(double* __restrict__ edge_acc, const unsigned int* __restrict__ edge_cnt) {
    size_t i = (size_t)blockIdx.x * 256 + threadIdx.x;
    if (i >= (size_t)N_EDGES * 32) return;
    unsigned int c = edge_cnt[i >> 5];
    double cc = (double)(c > 1u ? c : 1u);
    edge_acc[i] = edge_acc[i] / cc;
}

// half-wave per incidence: h_k = relu(p_a[v][k] + edge_proj[e][k] + b1[k]);
// logit = sum_k h_k*W2[k] + b2 ; prob = sigmoid(logit)
__global__ void logit_kernel(const int* __restrict__ V, const int* __restrict__ E,
                             const double* __restrict__ p_a, const double* __restrict__ edge_proj,
                             const float* __restrict__ b1, const float* __restrict__ W2,
                             const float* __restrict__ b2,
                             double* __restrict__ probs64, float* __restrict__ probs_out) {
    int j = blockIdx.x * 8 + (threadIdx.x >> 5);
    if (j >= NNZ) return;
    int k = threadIdx.x & 31;
    int v = V[j], e = E[j];
    double hk = p_a[(size_t)v * 32 + k] + edge_proj[(size_t)e * 32 + k] + (double)b1[k];
    hk = hk > 0.0 ? hk : 0.0;
    double t = hk * (double)W2[k];
    #pragma unroll
    for (int off = 16; off > 0; off >>= 1) t += __shfl_down(t, off, 32);
    if (k == 0) {
        double z = t + (double)b2[0];
        double pr = 1.0 / (1.0 + exp(-z));
        probs64[j] = pr;
        probs_out[j] = (float)pr;
    }
}

// ---------- radix select (descending) on f64 bit pattern (probs>0 -> monotonic) ----------
__global__ void histv_kernel(const double* __restrict__ probs64, const SelState* __restrict__ st,
                             unsigned int* __restrict__ hist, int pass) {
    __shared__ unsigned int lh[256];
    for (int t = threadIdx.x; t < 256; t += 256) lh[t] = 0;
    __syncthreads();
    unsigned long long prefix = st->prefix;
    unsigned long long mask = (pass == 7) ? 0ull : (~0ull << ((pass + 1) * 8));
    int shift = pass * 8;
    for (unsigned int i = blockIdx.x * blockDim.x + threadIdx.x; i < NNZ; i += gridDim.x * blockDim.x) {
        unsigned long long key = __double_as_longlong(probs64[i]);
        if ((key & mask) == prefix)
            atomicAdd(&lh[(key >> shift) & 255], 1u);
    }
    __syncthreads();
    for (int t = threadIdx.x; t < 256; t += 256)
        if (lh[t]) atomicAdd(&hist[pass * 256 + t], lh[t]);
}

__global__ void scanv_kernel(const unsigned int* __restrict__ hist, SelState* __restrict__ st, int pass) {
    if (threadIdx.x != 0) return;
    unsigned int kk = st->kk;
    const unsigned int* h = &hist[pass * 256];
    unsigned int cum = 0;
    int b;
    for (b = 255; b > 0; --b) {
        unsigned int c = h[b];
        if (kk <= cum + c) break;
        cum += c;
    }
    st->prefix |= ((unsigned long long)(unsigned int)b) << (pass * 8);
    st->kk = kk - cum;
    if (pass == 0) {         // value select done: rank among exact equals
        st->rr = kk - cum;
        st->idx_prefix = 0;
    }
}

// ---------- index radix select (ascending) among elements with key == T ----------
__global__ void histi_kernel(const double* __restrict__ probs64, const SelState* __restrict__ st,
                             unsigned int* __restrict__ hist, int qpass) {
    __shared__ unsigned int lh[128];
    for (int t = threadIdx.x; t < 128; t += 256) lh[t] = 0;
    __syncthreads();
    unsigned long long T = st->prefix;
    unsigned int ipref = st->idx_prefix;
    int shift = qpass * 7;
    unsigned int himask = ~((1u << (shift + 7)) - 1u);
    for (unsigned int i = blockIdx.x * blockDim.x + threadIdx.x; i < NNZ; i += gridDim.x * blockDim.x) {
        unsigned long long key = __double_as_longlong(probs64[i]);
        if (key == T && (i & himask) == ipref)
            atomicAdd(&lh[(i >> shift) & 127], 1u);
    }
    __syncthreads();
    for (int t = threadIdx.x; t < 128; t += 256)
        if (lh[t]) atomicAdd(&hist[qpass * 128 + t], lh[t]);
}

__global__ void scani_kernel(const unsigned int* __restrict__ hist, SelState* __restrict__ st, int qpass) {
    if (threadIdx.x != 0) return;
    unsigned int rr = st->rr;
    const unsigned int* h = &hist[qpass * 128];
    unsigned int cum = 0;
    int b;
    for (b = 0; b < 127; ++b) {
        unsigned int c = h[b];
        if (rr <= cum + c) break;
        cum += c;
    }
    st->idx_prefix |= ((unsigned int)b) << (qpass * 7);
    st->rr = rr - cum;
    if (qpass == 0) st->idx_thresh = st->idx_prefix;
}

// hard/soft per incidence + edge-level scatter sums
__global__ void final_inc_kernel(const double* __restrict__ probs64, const int* __restrict__ E,
                                 const SelState* __restrict__ st,
                                 float* __restrict__ soft, float* __restrict__ hard,
                                 double* __restrict__ eprob_sum, unsigned int* __restrict__ hard_cnt) {
    unsigned int i = blockIdx.x * 256 + threadIdx.x;
    if (i >= NNZ) return;
    double p = probs64[i];
    unsigned long long key = __double_as_longlong(p);
    unsigned long long T = st->prefix;
    bool hd = (key > T) || (key == T && i <= st->idx_thresh);
    float hf = hd ? 1.f : 0.f;
    hard[i] = hf;
    soft[i] = hf;   // (hard - probs) + probs == hard up to 1ulp; well within threshold
    int e = E[i];
    unsafeAtomicAdd(&eprob_sum[e], p);
    if (hd) atomicAdd(&hard_cnt[e], 1u);
}

__global__ void final_edge_kernel(const double* __restrict__ eprob_sum,
                                  const unsigned int* __restrict__ edge_cnt,
                                  const unsigned int* __restrict__ hard_cnt,
                                  float* __restrict__ o_ep, float* __restrict__ o_es, float* __restrict__ o_eh) {
    unsigned int e = blockIdx.x * 256 + threadIdx.x;
    if (e >= N_EDGES) return;
    unsigned int c = edge_cnt[e];
    double cc = (double)(c > 1u ? c : 1u);
    unsigned int hc = hard_cnt[e];
    o_ep[e] = (float)(eprob_sum[e] / cc);
    o_es[e] = (float)((double)hc / cc);
    o_eh[e] = (hc > 0u) ? 1.f : 0.f;
}

extern "C" void kernel_launch(void* const* d_in, const int* in_sizes, int n_in,
                              void* d_out, int out_size, void* d_ws, size_t ws_size,
                              hipStream_t stream) {
    const float* x  = (const float*)d_in[0];
    const int*   V  = (const int*)d_in[1];
    const int*   E  = (const int*)d_in[2];
    const float* W1 = (const float*)d_in[3];
    const float* b1 = (const float*)d_in[4];
    const float* W2 = (const float*)d_in[5];
    const float* b2 = (const float*)d_in[6];

    float* out     = (float*)d_out;
    float* o_probs = out;
    float* o_soft  = out + NNZ;
    float* o_hard  = out + 2 * (size_t)NNZ;
    float* o_ep    = out + 3 * (size_t)NNZ;
    float* o_es    = out + 3 * (size_t)NNZ + N_EDGES;
    float* o_eh    = out + 3 * (size_t)NNZ + 2 * (size_t)N_EDGES;

    char* w = (char*)d_ws;
    double*       p_a       = (double*)(w + OFF_PA);
    double*       p_b       = (double*)(w + OFF_PB);
    double*       probs64   = (double*)(w + OFF_P64);
    double*       edge_acc  = (double*)(w + OFF_EACC);
    double*       eprob_sum = (double*)(w + OFF_EPR);
    unsigned int* edge_cnt  = (unsigned int*)(w + OFF_ECNT);
    unsigned int* hard_cnt  = (unsigned int*)(w + OFF_HCNT);
    unsigned int* histv     = (unsigned int*)(w + OFF_HV);
    unsigned int* histi     = (unsigned int*)(w + OFF_HI);
    SelState*     st        = (SelState*)(w + OFF_ST);

    hipMemsetAsync(w + ZERO_OFF, 0, ZERO_LEN, stream);
    init_kernel<<<1, 64, 0, stream>>>(st);

    proj_kernel<<<(N_NODES + 7) / 8, 256, 0, stream>>>(x, W1, p_a, p_b);
    scatter_kernel<<<NNZ / 8, 256, 0, stream>>>(V, E, p_b, edge_acc, edge_cnt);
    edge_mean_kernel<<<(N_EDGES * 32 + 255) / 256, 256, 0, stream>>>(edge_acc, edge_cnt);
    logit_kernel<<<NNZ / 8, 256, 0, stream>>>(V, E, p_a, edge_acc, b1, W2, b2, probs64, o_probs);

    for (int p = 7; p >= 0; --p) {
        histv_kernel<<<1024, 256, 0, stream>>>(probs64, st, histv, p);
        scanv_kernel<<<1, 64, 0, stream>>>(histv, st, p);
    }
    for (int q = 2; q >= 0; --q) {
        histi_kernel<<<1024, 256, 0, stream>>>(probs64, st, histi, q);
        scani_kernel<<<1, 64, 0, stream>>>(histi, st, q);
    }

    final_inc_kernel<<<(NNZ + 255) / 256, 256, 0, stream>>>(probs64, E, st, o_soft, o_hard, eprob_sum, hard_cnt);
    final_edge_kernel<<<(N_EDGES + 255) / 256, 256, 0, stream>>>(eprob_sum, edge_cnt, hard_cnt, o_ep, o_es, o_eh);
}

// Round 2
// 1018.725 us; speedup vs baseline: 1.0719x; 1.0719x over previous
//
#include <hip/hip_runtime.h>
#include <math.h>

#define N_NODES   100000
#define N_EDGES   200000
#define NNZ       2000000
#define DD        64
#define HH        32
#define K_KEEP    1000000

// ---------------- workspace layout (bytes) ----------------
// p_a      f64 [N_NODES*32]   @ 0            25,600,000
// p_b      f64 [N_NODES*32]   @ 25,600,000   25,600,000
// probs64  f64 [NNZ]          @ 51,200,000   16,000,000   (vbucket u32[NNZ]=8MB aliases this; dead before logit)
// edge_acc f64 [N_EDGES*32]   @ 67,200,000   51,200,000   (fully overwritten by reduce; no zeroing)
// --- zero region start ---
// eprob    f64 [N_EDGES]      @ 118,400,000   1,600,000
// edge_cnt u32 [N_EDGES]      @ 120,000,000     800,000
// hard_cnt u32 [N_EDGES]      @ 120,800,000     800,000
// histv    u32 [8*256]        @ 121,600,000       8,192
// histi    u32 [3*128]        @ 121,608,192       1,536
// state                       @ 121,609,728          64
// --- zero region end: 121,609,792 ---
// edge_off u32 [N_EDGES]      @ 121,609,792     800,000
// cursor   u32 [N_EDGES]      @ 122,409,792     800,000
// bsums    u32 [256]          @ 123,209,792       1,024
// total: 123,210,816
#define OFF_PA    ((size_t)0)
#define OFF_PB    ((size_t)25600000)
#define OFF_P64   ((size_t)51200000)
#define OFF_EACC  ((size_t)67200000)
#define OFF_EPR   ((size_t)118400000)
#define OFF_ECNT  ((size_t)120000000)
#define OFF_HCNT  ((size_t)120800000)
#define OFF_HV    ((size_t)121600000)
#define OFF_HI    ((size_t)121608192)
#define OFF_ST    ((size_t)121609728)
#define OFF_EOFF  ((size_t)121609792)
#define OFF_CUR   ((size_t)122409792)
#define OFF_BS    ((size_t)123209792)
#define ZERO_OFF  OFF_EPR
#define ZERO_LEN  ((size_t)(121609792 - 118400000))

#define SCAN_BLOCKS 196   // ceil(200000 / 1024)

struct SelState {
    unsigned long long prefix;     // value-select key prefix (f64 bits of T)
    unsigned int kk;               // remaining descending rank
    unsigned int rr;               // remaining ascending rank among equals
    unsigned int idx_prefix;       // index-select prefix
    unsigned int idx_thresh;       // final: index of r-th smallest equal
};

__global__ void init_kernel(SelState* st) {
    if (threadIdx.x == 0) {
        st->prefix = 0ull;
        st->kk = K_KEEP;
        st->rr = 0;
        st->idx_prefix = 0;
        st->idx_thresh = 0;
    }
}

// p_a[v][k] = sum_d x[v][d] * W1[d][k]; p_b[v][k] = sum_d x[v][d] * W1[64+d][k]
__global__ void proj_kernel(const float* __restrict__ x, const float* __restrict__ W1,
                            double* __restrict__ p_a, double* __restrict__ p_b) {
    __shared__ float sW[128 * 32];   // 16 KB
    __shared__ float sx[8][64];      // 2 KB
    for (int t = threadIdx.x; t < 128 * 32; t += 256) sW[t] = W1[t];
    int base = blockIdx.x * 8;
    for (int t = threadIdx.x; t < 512; t += 256) {
        int n = t >> 6, d = t & 63;
        int g = base + n;
        sx[n][d] = (g < N_NODES) ? x[(size_t)g * DD + d] : 0.f;
    }
    __syncthreads();
    int ln = threadIdx.x >> 5;
    int k  = threadIdx.x & 31;
    int node = base + ln;
    if (node >= N_NODES) return;
    double sa = 0.0, sb = 0.0;
    for (int d = 0; d < 64; ++d) {
        double xv = (double)sx[ln][d];
        sa += xv * (double)sW[d * 32 + k];
        sb += xv * (double)sW[(64 + d) * 32 + k];
    }
    p_a[(size_t)node * 32 + k] = sa;
    p_b[(size_t)node * 32 + k] = sb;
}

// ---------------- CSR build: count -> scan -> bucket ----------------
__global__ void count_kernel(const int* __restrict__ E, unsigned int* __restrict__ edge_cnt) {
    int j = blockIdx.x * 256 + threadIdx.x;
    if (j >= NNZ) return;
    atomicAdd(&edge_cnt[E[j]], 1u);
}

// each block scans 1024 counts (4/thread); writes per-element exclusive partials + block sum
__global__ void scanA_kernel(const unsigned int* __restrict__ edge_cnt,
                             unsigned int* __restrict__ edge_off, unsigned int* __restrict__ bsums) {
    __shared__ unsigned int s[256];
    int tid = threadIdx.x;
    int base = blockIdx.x * 1024 + tid * 4;
    unsigned int v0 = (base + 0 < N_EDGES) ? edge_cnt[base + 0] : 0u;
    unsigned int v1 = (base + 1 < N_EDGES) ? edge_cnt[base + 1] : 0u;
    unsigned int v2 = (base + 2 < N_EDGES) ? edge_cnt[base + 2] : 0u;
    unsigned int v3 = (base + 3 < N_EDGES) ? edge_cnt[base + 3] : 0u;
    unsigned int tsum = v0 + v1 + v2 + v3;
    s[tid] = tsum;
    __syncthreads();
    for (int off = 1; off < 256; off <<= 1) {
        unsigned int t = (tid >= off) ? s[tid - off] : 0u;
        __syncthreads();
        s[tid] += t;
        __syncthreads();
    }
    unsigned int excl = s[tid] - tsum;
    if (base + 0 < N_EDGES) edge_off[base + 0] = excl;
    if (base + 1 < N_EDGES) edge_off[base + 1] = excl + v0;
    if (base + 2 < N_EDGES) edge_off[base + 2] = excl + v0 + v1;
    if (base + 3 < N_EDGES) edge_off[base + 3] = excl + v0 + v1 + v2;
    if (tid == 255) bsums[blockIdx.x] = s[255];
}

__global__ void scanB_kernel(unsigned int* __restrict__ bsums) {
    __shared__ unsigned int s[256];
    int tid = threadIdx.x;
    unsigned int v = (tid < SCAN_BLOCKS) ? bsums[tid] : 0u;
    s[tid] = v;
    __syncthreads();
    for (int off = 1; off < 256; off <<= 1) {
        unsigned int t = (tid >= off) ? s[tid - off] : 0u;
        __syncthreads();
        s[tid] += t;
        __syncthreads();
    }
    if (tid < SCAN_BLOCKS) bsums[tid] = s[tid] - v;   // exclusive
}

__global__ void scanC_kernel(unsigned int* __restrict__ edge_off, const unsigned int* __restrict__ bsums,
                             unsigned int* __restrict__ cursor) {
    int i = blockIdx.x * 256 + threadIdx.x;
    if (i >= N_EDGES) return;
    unsigned int o = edge_off[i] + bsums[i >> 10];
    edge_off[i] = o;
    cursor[i] = o;
}

__global__ void bucket_kernel(const int* __restrict__ V, const int* __restrict__ E,
                              unsigned int* __restrict__ cursor, unsigned int* __restrict__ vbucket) {
    int j = blockIdx.x * 256 + threadIdx.x;
    if (j >= NNZ) return;
    int e = E[j];
    unsigned int p = atomicAdd(&cursor[e], 1u);
    vbucket[p] = (unsigned int)V[j];
}

// one 32-lane half-wave per edge: edge_acc[e][k] = mean_i p_b[vlist[i]][k]
__global__ void reduce_kernel(const unsigned int* __restrict__ vbucket,
                              const unsigned int* __restrict__ edge_off,
                              const unsigned int* __restrict__ edge_cnt,
                              const double* __restrict__ p_b,
                              double* __restrict__ edge_acc) {
    int e = blockIdx.x * 8 + (threadIdx.x >> 5);
    if (e >= N_EDGES) return;
    int k = threadIdx.x & 31;
    unsigned int off = edge_off[e];
    unsigned int deg = edge_cnt[e];
    double acc = 0.0;
    for (unsigned int i = 0; i < deg; ++i) {
        unsigned int v = vbucket[off + i];
        acc += p_b[(size_t)v * 32 + k];
    }
    double cc = (double)(deg > 1u ? deg : 1u);
    edge_acc[(size_t)e * 32 + k] = acc / cc;
}

// half-wave per incidence: h_k = relu(p_a[v][k] + edge_proj[e][k] + b1[k]);
// logit = sum_k h_k*W2[k] + b2 ; prob = sigmoid(logit)
__global__ void logit_kernel(const int* __restrict__ V, const int* __restrict__ E,
                             const double* __restrict__ p_a, const double* __restrict__ edge_proj,
                             const float* __restrict__ b1, const float* __restrict__ W2,
                             const float* __restrict__ b2,
                             double* __restrict__ probs64, float* __restrict__ probs_out) {
    int j = blockIdx.x * 8 + (threadIdx.x >> 5);
    if (j >= NNZ) return;
    int k = threadIdx.x & 31;
    int v = V[j], e = E[j];
    double hk = p_a[(size_t)v * 32 + k] + edge_proj[(size_t)e * 32 + k] + (double)b1[k];
    hk = hk > 0.0 ? hk : 0.0;
    double t = hk * (double)W2[k];
    #pragma unroll
    for (int off = 16; off > 0; off >>= 1) t += __shfl_down(t, off, 32);
    if (k == 0) {
        double z = t + (double)b2[0];
        double pr = 1.0 / (1.0 + exp(-z));
        probs64[j] = pr;
        probs_out[j] = (float)pr;
    }
}

// ---------- radix select (descending) on f64 bit pattern (probs>0 -> monotonic) ----------
__global__ void histv_kernel(const double* __restrict__ probs64, const SelState* __restrict__ st,
                             unsigned int* __restrict__ hist, int pass) {
    __shared__ unsigned int lh[256];
    for (int t = threadIdx.x; t < 256; t += 256) lh[t] = 0;
    __syncthreads();
    unsigned long long prefix = st->prefix;
    unsigned long long mask = (pass == 7) ? 0ull : (~0ull << ((pass + 1) * 8));
    int shift = pass * 8;
    for (unsigned int i = blockIdx.x * blockDim.x + threadIdx.x; i < NNZ; i += gridDim.x * blockDim.x) {
        unsigned long long key = __double_as_longlong(probs64[i]);
        if ((key & mask) == prefix)
            atomicAdd(&lh[(key >> shift) & 255], 1u);
    }
    __syncthreads();
    for (int t = threadIdx.x; t < 256; t += 256)
        if (lh[t]) atomicAdd(&hist[pass * 256 + t], lh[t]);
}

__global__ void scanv_kernel(const unsigned int* __restrict__ hist, SelState* __restrict__ st, int pass) {
    if (threadIdx.x != 0) return;
    unsigned int kk = st->kk;
    const unsigned int* h = &hist[pass * 256];
    unsigned int cum = 0;
    int b;
    for (b = 255; b > 0; --b) {
        unsigned int c = h[b];
        if (kk <= cum + c) break;
        cum += c;
    }
    st->prefix |= ((unsigned long long)(unsigned int)b) << (pass * 8);
    st->kk = kk - cum;
    if (pass == 0) {         // value select done: rank among exact equals
        st->rr = kk - cum;
        st->idx_prefix = 0;
    }
}

// ---------- index radix select (ascending) among elements with key == T ----------
__global__ void histi_kernel(const double* __restrict__ probs64, const SelState* __restrict__ st,
                             unsigned int* __restrict__ hist, int qpass) {
    __shared__ unsigned int lh[128];
    for (int t = threadIdx.x; t < 128; t += 256) lh[t] = 0;
    __syncthreads();
    unsigned long long T = st->prefix;
    unsigned int ipref = st->idx_prefix;
    int shift = qpass * 7;
    unsigned int himask = ~((1u << (shift + 7)) - 1u);
    for (unsigned int i = blockIdx.x * blockDim.x + threadIdx.x; i < NNZ; i += gridDim.x * blockDim.x) {
        unsigned long long key = __double_as_longlong(probs64[i]);
        if (key == T && (i & himask) == ipref)
            atomicAdd(&lh[(i >> shift) & 127], 1u);
    }
    __syncthreads();
    for (int t = threadIdx.x; t < 128; t += 256)
        if (lh[t]) atomicAdd(&hist[qpass * 128 + t], lh[t]);
}

__global__ void scani_kernel(const unsigned int* __restrict__ hist, SelState* __restrict__ st, int qpass) {
    if (threadIdx.x != 0) return;
    unsigned int rr = st->rr;
    const unsigned int* h = &hist[qpass * 128];
    unsigned int cum = 0;
    int b;
    for (b = 0; b < 127; ++b) {
        unsigned int c = h[b];
        if (rr <= cum + c) break;
        cum += c;
    }
    st->idx_prefix |= ((unsigned int)b) << (qpass * 7);
    st->rr = rr - cum;
    if (qpass == 0) st->idx_thresh = st->idx_prefix;
}

// hard/soft per incidence + edge-level scatter sums
__global__ void final_inc_kernel(const double* __restrict__ probs64, const int* __restrict__ E,
                                 const SelState* __restrict__ st,
                                 float* __restrict__ soft, float* __restrict__ hard,
                                 double* __restrict__ eprob_sum, unsigned int* __restrict__ hard_cnt) {
    unsigned int i = blockIdx.x * 256 + threadIdx.x;
    if (i >= NNZ) return;
    double p = probs64[i];
    unsigned long long key = __double_as_longlong(p);
    unsigned long long T = st->prefix;
    bool hd = (key > T) || (key == T && i <= st->idx_thresh);
    float hf = hd ? 1.f : 0.f;
    hard[i] = hf;
    soft[i] = hf;   // (hard - probs) + probs == hard up to 1ulp; well within threshold
    int e = E[i];
    unsafeAtomicAdd(&eprob_sum[e], p);
    if (hd) atomicAdd(&hard_cnt[e], 1u);
}

__global__ void final_edge_kernel(const double* __restrict__ eprob_sum,
                                  const unsigned int* __restrict__ edge_cnt,
                                  const unsigned int* __restrict__ hard_cnt,
                                  float* __restrict__ o_ep, float* __restrict__ o_es, float* __restrict__ o_eh) {
    unsigned int e = blockIdx.x * 256 + threadIdx.x;
    if (e >= N_EDGES) return;
    unsigned int c = edge_cnt[e];
    double cc = (double)(c > 1u ? c : 1u);
    unsigned int hc = hard_cnt[e];
    o_ep[e] = (float)(eprob_sum[e] / cc);
    o_es[e] = (float)((double)hc / cc);
    o_eh[e] = (hc > 0u) ? 1.f : 0.f;
}

extern "C" void kernel_launch(void* const* d_in, const int* in_sizes, int n_in,
                              void* d_out, int out_size, void* d_ws, size_t ws_size,
                              hipStream_t stream) {
    const float* x  = (const float*)d_in[0];
    const int*   V  = (const int*)d_in[1];
    const int*   E  = (const int*)d_in[2];
    const float* W1 = (const float*)d_in[3];
    const float* b1 = (const float*)d_in[4];
    const float* W2 = (const float*)d_in[5];
    const float* b2 = (const float*)d_in[6];

    float* out     = (float*)d_out;
    float* o_probs = out;
    float* o_soft  = out + NNZ;
    float* o_hard  = out + 2 * (size_t)NNZ;
    float* o_ep    = out + 3 * (size_t)NNZ;
    float* o_es    = out + 3 * (size_t)NNZ + N_EDGES;
    float* o_eh    = out + 3 * (size_t)NNZ + 2 * (size_t)N_EDGES;

    char* w = (char*)d_ws;
    double*       p_a       = (double*)(w + OFF_PA);
    double*       p_b       = (double*)(w + OFF_PB);
    double*       probs64   = (double*)(w + OFF_P64);
    unsigned int* vbucket   = (unsigned int*)(w + OFF_P64);   // alias: dead before logit
    double*       edge_acc  = (double*)(w + OFF_EACC);
    double*       eprob_sum = (double*)(w + OFF_EPR);
    unsigned int* edge_cnt  = (unsigned int*)(w + OFF_ECNT);
    unsigned int* hard_cnt  = (unsigned int*)(w + OFF_HCNT);
    unsigned int* histv     = (unsigned int*)(w + OFF_HV);
    unsigned int* histi     = (unsigned int*)(w + OFF_HI);
    SelState*     st        = (SelState*)(w + OFF_ST);
    unsigned int* edge_off  = (unsigned int*)(w + OFF_EOFF);
    unsigned int* cursor    = (unsigned int*)(w + OFF_CUR);
    unsigned int* bsums     = (unsigned int*)(w + OFF_BS);

    hipMemsetAsync(w + ZERO_OFF, 0, ZERO_LEN, stream);
    init_kernel<<<1, 64, 0, stream>>>(st);

    proj_kernel<<<(N_NODES + 7) / 8, 256, 0, stream>>>(x, W1, p_a, p_b);

    count_kernel<<<(NNZ + 255) / 256, 256, 0, stream>>>(E, edge_cnt);
    scanA_kernel<<<SCAN_BLOCKS, 256, 0, stream>>>(edge_cnt, edge_off, bsums);
    scanB_kernel<<<1, 256, 0, stream>>>(bsums);
    scanC_kernel<<<(N_EDGES + 255) / 256, 256, 0, stream>>>(edge_off, bsums, cursor);
    bucket_kernel<<<(NNZ + 255) / 256, 256, 0, stream>>>(V, E, cursor, vbucket);
    reduce_kernel<<<N_EDGES / 8, 256, 0, stream>>>(vbucket, edge_off, edge_cnt, p_b, edge_acc);

    logit_kernel<<<NNZ / 8, 256, 0, stream>>>(V, E, p_a, edge_acc, b1, W2, b2, probs64, o_probs);

    for (int p = 7; p >= 0; --p) {
        histv_kernel<<<1024, 256, 0, stream>>>(probs64, st, histv, p);
        scanv_kernel<<<1, 64, 0, stream>>>(histv, st, p);
    }
    for (int q = 2; q >= 0; --q) {
        histi_kernel<<<1024, 256, 0, stream>>>(probs64, st, histi, q);
        scani_kernel<<<1, 64, 0, stream>>>(histi, st, q);
    }

    final_inc_kernel<<<(NNZ + 255) / 256, 256, 0, stream>>>(probs64, E, st, o_soft, o_hard, eprob_sum, hard_cnt);
    final_edge_kernel<<<(N_EDGES + 255) / 256, 256, 0, stream>>>(eprob_sum, edge_cnt, hard_cnt, o_ep, o_es, o_eh);
}

// Round 3
// 956.303 us; speedup vs baseline: 1.1419x; 1.0653x over previous
//
#include <hip/hip_runtime.h>
#include <math.h>

#define N_NODES   100000
#define N_EDGES   200000
#define NNZ       2000000
#define DD        64
#define HH        32
#define K_KEEP    1000000

// ---------------- workspace layout (bytes) ----------------
// p_ab     f64 [N_NODES*64]   @ 0            51,200,000   (row: a[0..31] | b[32..63])
// probs64  f64 [NNZ]          @ 51,200,000   16,000,000
// vbucket  u32 [NNZ]          @ 67,200,000    8,000,000
// jbucket  u32 [NNZ]          @ 75,200,000    8,000,000
// --- zero region start ---
// eprob    f64 [N_EDGES]      @ 118,400,000   1,600,000
// edge_cnt u32 [N_EDGES]      @ 120,000,000     800,000
// hard_cnt u32 [N_EDGES]      @ 120,800,000     800,000
// histv    u32 [8*256]        @ 121,600,000       8,192
// histi    u32 [3*128]        @ 121,608,192       1,536
// state                       @ 121,609,728          64
// --- zero region end: 121,609,792 ---
// edge_off u32 [N_EDGES]      @ 121,609,792     800,000
// cursor   u32 [N_EDGES]      @ 122,409,792     800,000
// bsums    u32 [256]          @ 123,209,792       1,024
// total: 123,210,816 (same as R1)
#define OFF_PAB   ((size_t)0)
#define OFF_P64   ((size_t)51200000)
#define OFF_VB    ((size_t)67200000)
#define OFF_JB    ((size_t)75200000)
#define OFF_EPR   ((size_t)118400000)
#define OFF_ECNT  ((size_t)120000000)
#define OFF_HCNT  ((size_t)120800000)
#define OFF_HV    ((size_t)121600000)
#define OFF_HI    ((size_t)121608192)
#define OFF_ST    ((size_t)121609728)
#define OFF_EOFF  ((size_t)121609792)
#define OFF_CUR   ((size_t)122409792)
#define OFF_BS    ((size_t)123209792)
#define ZERO_OFF  OFF_EPR
#define ZERO_LEN  ((size_t)(121609792 - 118400000))

#define SCAN_BLOCKS 196   // ceil(200000 / 1024)
#define MAXU 16           // register stash per half-lane: covers deg <= 32

struct SelState {
    unsigned long long prefix;
    unsigned int kk;
    unsigned int rr;
    unsigned int idx_prefix;
    unsigned int idx_thresh;
};

__global__ void init_kernel(SelState* st) {
    if (threadIdx.x == 0) {
        st->prefix = 0ull;
        st->kk = K_KEEP;
        st->rr = 0;
        st->idx_prefix = 0;
        st->idx_thresh = 0;
    }
}

// p_ab[v][k] = sum_d x[v][d]*W1[d][k];  p_ab[v][32+k] = sum_d x[v][d]*W1[64+d][k]
__global__ void proj_kernel(const float* __restrict__ x, const float* __restrict__ W1,
                            double* __restrict__ p_ab) {
    __shared__ float sW[128 * 32];   // 16 KB
    __shared__ float sx[8][64];      // 2 KB
    for (int t = threadIdx.x; t < 128 * 32; t += 256) sW[t] = W1[t];
    int base = blockIdx.x * 8;
    for (int t = threadIdx.x; t < 512; t += 256) {
        int n = t >> 6, d = t & 63;
        int g = base + n;
        sx[n][d] = (g < N_NODES) ? x[(size_t)g * DD + d] : 0.f;
    }
    __syncthreads();
    int ln = threadIdx.x >> 5;
    int k  = threadIdx.x & 31;
    int node = base + ln;
    if (node >= N_NODES) return;
    double sa = 0.0, sb = 0.0;
    for (int d = 0; d < 64; ++d) {
        double xv = (double)sx[ln][d];
        sa += xv * (double)sW[d * 32 + k];
        sb += xv * (double)sW[(64 + d) * 32 + k];
    }
    p_ab[(size_t)node * 64 + k]      = sa;
    p_ab[(size_t)node * 64 + 32 + k] = sb;
}

// ---------------- CSR build: count -> scan -> bucket ----------------
__global__ void count_kernel(const int* __restrict__ E, unsigned int* __restrict__ edge_cnt) {
    int j = blockIdx.x * 256 + threadIdx.x;
    if (j >= NNZ) return;
    atomicAdd(&edge_cnt[E[j]], 1u);
}

__global__ void scanA_kernel(const unsigned int* __restrict__ edge_cnt,
                             unsigned int* __restrict__ edge_off, unsigned int* __restrict__ bsums) {
    __shared__ unsigned int s[256];
    int tid = threadIdx.x;
    int base = blockIdx.x * 1024 + tid * 4;
    unsigned int v0 = (base + 0 < N_EDGES) ? edge_cnt[base + 0] : 0u;
    unsigned int v1 = (base + 1 < N_EDGES) ? edge_cnt[base + 1] : 0u;
    unsigned int v2 = (base + 2 < N_EDGES) ? edge_cnt[base + 2] : 0u;
    unsigned int v3 = (base + 3 < N_EDGES) ? edge_cnt[base + 3] : 0u;
    unsigned int tsum = v0 + v1 + v2 + v3;
    s[tid] = tsum;
    __syncthreads();
    for (int off = 1; off < 256; off <<= 1) {
        unsigned int t = (tid >= off) ? s[tid - off] : 0u;
        __syncthreads();
        s[tid] += t;
        __syncthreads();
    }
    unsigned int excl = s[tid] - tsum;
    if (base + 0 < N_EDGES) edge_off[base + 0] = excl;
    if (base + 1 < N_EDGES) edge_off[base + 1] = excl + v0;
    if (base + 2 < N_EDGES) edge_off[base + 2] = excl + v0 + v1;
    if (base + 3 < N_EDGES) edge_off[base + 3] = excl + v0 + v1 + v2;
    if (tid == 255) bsums[blockIdx.x] = s[255];
}

__global__ void scanB_kernel(unsigned int* __restrict__ bsums) {
    __shared__ unsigned int s[256];
    int tid = threadIdx.x;
    unsigned int v = (tid < SCAN_BLOCKS) ? bsums[tid] : 0u;
    s[tid] = v;
    __syncthreads();
    for (int off = 1; off < 256; off <<= 1) {
        unsigned int t = (tid >= off) ? s[tid - off] : 0u;
        __syncthreads();
        s[tid] += t;
        __syncthreads();
    }
    if (tid < SCAN_BLOCKS) bsums[tid] = s[tid] - v;   // exclusive
}

__global__ void scanC_kernel(unsigned int* __restrict__ edge_off, const unsigned int* __restrict__ bsums,
                             unsigned int* __restrict__ cursor) {
    int i = blockIdx.x * 256 + threadIdx.x;
    if (i >= N_EDGES) return;
    unsigned int o = edge_off[i] + bsums[i >> 10];
    edge_off[i] = o;
    cursor[i] = o;
}

__global__ void bucket_kernel(const int* __restrict__ V, const int* __restrict__ E,
                              unsigned int* __restrict__ cursor,
                              unsigned int* __restrict__ vbucket, unsigned int* __restrict__ jbucket) {
    int j = blockIdx.x * 256 + threadIdx.x;
    if (j >= NNZ) return;
    int e = E[j];
    unsigned int p = atomicAdd(&cursor[e], 1u);
    vbucket[p] = (unsigned int)V[j];
    jbucket[p] = (unsigned int)j;
}

// ---------------- fused per-edge mean + per-incidence MLP ----------------
// one 64-lane wave per edge; half h handles incidences i = h, h+2, h+4, ...
// pass 1: gather p_ab rows (a-half stashed in regs, b-half accumulated);
// pass 2: h_k = relu(a_vk + mean_b_ek + b1_k); logit = sum_k h_k*W2_k + b2
__global__ void edge_logit_kernel(const unsigned int* __restrict__ vbucket,
                                  const unsigned int* __restrict__ jbucket,
                                  const unsigned int* __restrict__ edge_off,
                                  const unsigned int* __restrict__ edge_cnt,
                                  const double* __restrict__ p_ab,
                                  const float* __restrict__ b1, const float* __restrict__ W2,
                                  const float* __restrict__ b2,
                                  double* __restrict__ probs64, float* __restrict__ probs_out) {
    int e = blockIdx.x * 4 + (threadIdx.x >> 6);
    if (e >= N_EDGES) return;
    int lane = threadIdx.x & 63;
    int k    = lane & 31;
    unsigned int half = (unsigned int)(lane >> 5);

    unsigned int off = edge_off[e];
    unsigned int deg = edge_cnt[e];

    double aval[MAXU];
    unsigned int jv[MAXU];
    double bacc = 0.0;

    #pragma unroll
    for (int idx = 0; idx < MAXU; ++idx) {
        unsigned int i = half + 2u * (unsigned int)idx;
        if (i < deg) {
            unsigned int v = vbucket[off + i];
            const double* row = p_ab + (size_t)v * 64u;
            aval[idx] = row[k];
            bacc     += row[32 + k];
            jv[idx]   = jbucket[off + i];
        }
    }
    if (deg > 2u * MAXU) {   // rare overflow (Poisson(10) tail)
        for (unsigned int i = half + 2u * MAXU; i < deg; i += 2u) {
            unsigned int v = vbucket[off + i];
            bacc += p_ab[(size_t)v * 64u + 32u + k];
        }
    }

    double cc  = (double)(deg > 1u ? deg : 1u);
    double emk = (bacc + __shfl_xor(bacc, 32)) / cc + (double)b1[k];
    double w2k = (double)W2[k];
    double b2v = (double)b2[0];

    #pragma unroll
    for (int idx = 0; idx < MAXU; ++idx) {
        unsigned int i = half + 2u * (unsigned int)idx;
        if (i < deg) {
            double hk = aval[idx] + emk;
            hk = hk > 0.0 ? hk : 0.0;
            double t = hk * w2k;
            #pragma unroll
            for (int o = 16; o > 0; o >>= 1) t += __shfl_down(t, o, 32);
            if (k == 0) {
                double z  = t + b2v;
                double pr = 1.0 / (1.0 + exp(-z));
                unsigned int j = jv[idx];
                probs64[j]   = pr;
                probs_out[j] = (float)pr;
            }
        }
    }
    if (deg > 2u * MAXU) {
        for (unsigned int i = half + 2u * MAXU; i < deg; i += 2u) {
            unsigned int v = vbucket[off + i];
            unsigned int j = jbucket[off + i];
            double hk = p_ab[(size_t)v * 64u + k] + emk;
            hk = hk > 0.0 ? hk : 0.0;
            double t = hk * w2k;
            #pragma unroll
            for (int o = 16; o > 0; o >>= 1) t += __shfl_down(t, o, 32);
            if (k == 0) {
                double z  = t + b2v;
                double pr = 1.0 / (1.0 + exp(-z));
                probs64[j]   = pr;
                probs_out[j] = (float)pr;
            }
        }
    }
}

// ---------- radix select (descending) on f64 bit pattern (probs>0 -> monotonic) ----------
__global__ void histv_kernel(const double* __restrict__ probs64, const SelState* __restrict__ st,
                             unsigned int* __restrict__ hist, int pass) {
    __shared__ unsigned int lh[256];
    for (int t = threadIdx.x; t < 256; t += 256) lh[t] = 0;
    __syncthreads();
    unsigned long long prefix = st->prefix;
    unsigned long long mask = (pass == 7) ? 0ull : (~0ull << ((pass + 1) * 8));
    int shift = pass * 8;
    for (unsigned int i = blockIdx.x * blockDim.x + threadIdx.x; i < NNZ; i += gridDim.x * blockDim.x) {
        unsigned long long key = __double_as_longlong(probs64[i]);
        if ((key & mask) == prefix)
            atomicAdd(&lh[(key >> shift) & 255], 1u);
    }
    __syncthreads();
    for (int t = threadIdx.x; t < 256; t += 256)
        if (lh[t]) atomicAdd(&hist[pass * 256 + t], lh[t]);
}

__global__ void scanv_kernel(const unsigned int* __restrict__ hist, SelState* __restrict__ st, int pass) {
    if (threadIdx.x != 0) return;
    unsigned int kk = st->kk;
    const unsigned int* h = &hist[pass * 256];
    unsigned int cum = 0;
    int b;
    for (b = 255; b > 0; --b) {
        unsigned int c = h[b];
        if (kk <= cum + c) break;
        cum += c;
    }
    st->prefix |= ((unsigned long long)(unsigned int)b) << (pass * 8);
    st->kk = kk - cum;
    if (pass == 0) {
        st->rr = kk - cum;
        st->idx_prefix = 0;
    }
}

// ---------- index radix select (ascending) among elements with key == T ----------
__global__ void histi_kernel(const double* __restrict__ probs64, const SelState* __restrict__ st,
                             unsigned int* __restrict__ hist, int qpass) {
    __shared__ unsigned int lh[128];
    for (int t = threadIdx.x; t < 128; t += 256) lh[t] = 0;
    __syncthreads();
    unsigned long long T = st->prefix;
    unsigned int ipref = st->idx_prefix;
    int shift = qpass * 7;
    unsigned int himask = ~((1u << (shift + 7)) - 1u);
    for (unsigned int i = blockIdx.x * blockDim.x + threadIdx.x; i < NNZ; i += gridDim.x * blockDim.x) {
        unsigned long long key = __double_as_longlong(probs64[i]);
        if (key == T && (i & himask) == ipref)
            atomicAdd(&lh[(i >> shift) & 127], 1u);
    }
    __syncthreads();
    for (int t = threadIdx.x; t < 128; t += 256)
        if (lh[t]) atomicAdd(&hist[qpass * 128 + t], lh[t]);
}

__global__ void scani_kernel(const unsigned int* __restrict__ hist, SelState* __restrict__ st, int qpass) {
    if (threadIdx.x != 0) return;
    unsigned int rr = st->rr;
    const unsigned int* h = &hist[qpass * 128];
    unsigned int cum = 0;
    int b;
    for (b = 0; b < 127; ++b) {
        unsigned int c = h[b];
        if (rr <= cum + c) break;
        cum += c;
    }
    st->idx_prefix |= ((unsigned int)b) << (qpass * 7);
    st->rr = rr - cum;
    if (qpass == 0) st->idx_thresh = st->idx_prefix;
}

// hard/soft per incidence + edge-level scatter sums
__global__ void final_inc_kernel(const double* __restrict__ probs64, const int* __restrict__ E,
                                 const SelState* __restrict__ st,
                                 float* __restrict__ soft, float* __restrict__ hard,
                                 double* __restrict__ eprob_sum, unsigned int* __restrict__ hard_cnt) {
    unsigned int i = blockIdx.x * 256 + threadIdx.x;
    if (i >= NNZ) return;
    double p = probs64[i];
    unsigned long long key = __double_as_longlong(p);
    unsigned long long T = st->prefix;
    bool hd = (key > T) || (key == T && i <= st->idx_thresh);
    float hf = hd ? 1.f : 0.f;
    hard[i] = hf;
    soft[i] = hf;
    int e = E[i];
    unsafeAtomicAdd(&eprob_sum[e], p);
    if (hd) atomicAdd(&hard_cnt[e], 1u);
}

__global__ void final_edge_kernel(const double* __restrict__ eprob_sum,
                                  const unsigned int* __restrict__ edge_cnt,
                                  const unsigned int* __restrict__ hard_cnt,
                                  float* __restrict__ o_ep, float* __restrict__ o_es, float* __restrict__ o_eh) {
    unsigned int e = blockIdx.x * 256 + threadIdx.x;
    if (e >= N_EDGES) return;
    unsigned int c = edge_cnt[e];
    double cc = (double)(c > 1u ? c : 1u);
    unsigned int hc = hard_cnt[e];
    o_ep[e] = (float)(eprob_sum[e] / cc);
    o_es[e] = (float)((double)hc / cc);
    o_eh[e] = (hc > 0u) ? 1.f : 0.f;
}

extern "C" void kernel_launch(void* const* d_in, const int* in_sizes, int n_in,
                              void* d_out, int out_size, void* d_ws, size_t ws_size,
                              hipStream_t stream) {
    const float* x  = (const float*)d_in[0];
    const int*   V  = (const int*)d_in[1];
    const int*   E  = (const int*)d_in[2];
    const float* W1 = (const float*)d_in[3];
    const float* b1 = (const float*)d_in[4];
    const float* W2 = (const float*)d_in[5];
    const float* b2 = (const float*)d_in[6];

    float* out     = (float*)d_out;
    float* o_probs = out;
    float* o_soft  = out + NNZ;
    float* o_hard  = out + 2 * (size_t)NNZ;
    float* o_ep    = out + 3 * (size_t)NNZ;
    float* o_es    = out + 3 * (size_t)NNZ + N_EDGES;
    float* o_eh    = out + 3 * (size_t)NNZ + 2 * (size_t)N_EDGES;

    char* w = (char*)d_ws;
    double*       p_ab      = (double*)(w + OFF_PAB);
    double*       probs64   = (double*)(w + OFF_P64);
    unsigned int* vbucket   = (unsigned int*)(w + OFF_VB);
    unsigned int* jbucket   = (unsigned int*)(w + OFF_JB);
    double*       eprob_sum = (double*)(w + OFF_EPR);
    unsigned int* edge_cnt  = (unsigned int*)(w + OFF_ECNT);
    unsigned int* hard_cnt  = (unsigned int*)(w + OFF_HCNT);
    unsigned int* histv     = (unsigned int*)(w + OFF_HV);
    unsigned int* histi     = (unsigned int*)(w + OFF_HI);
    SelState*     st        = (SelState*)(w + OFF_ST);
    unsigned int* edge_off  = (unsigned int*)(w + OFF_EOFF);
    unsigned int* cursor    = (unsigned int*)(w + OFF_CUR);
    unsigned int* bsums     = (unsigned int*)(w + OFF_BS);

    hipMemsetAsync(w + ZERO_OFF, 0, ZERO_LEN, stream);
    init_kernel<<<1, 64, 0, stream>>>(st);

    proj_kernel<<<(N_NODES + 7) / 8, 256, 0, stream>>>(x, W1, p_ab);

    count_kernel<<<(NNZ + 255) / 256, 256, 0, stream>>>(E, edge_cnt);
    scanA_kernel<<<SCAN_BLOCKS, 256, 0, stream>>>(edge_cnt, edge_off, bsums);
    scanB_kernel<<<1, 256, 0, stream>>>(bsums);
    scanC_kernel<<<(N_EDGES + 255) / 256, 256, 0, stream>>>(edge_off, bsums, cursor);
    bucket_kernel<<<(NNZ + 255) / 256, 256, 0, stream>>>(V, E, cursor, vbucket, jbucket);

    edge_logit_kernel<<<(N_EDGES + 3) / 4, 256, 0, stream>>>(vbucket, jbucket, edge_off, edge_cnt,
                                                             p_ab, b1, W2, b2, probs64, o_probs);

    for (int p = 7; p >= 0; --p) {
        histv_kernel<<<1024, 256, 0, stream>>>(probs64, st, histv, p);
        scanv_kernel<<<1, 64, 0, stream>>>(histv, st, p);
    }
    for (int q = 2; q >= 0; --q) {
        histi_kernel<<<1024, 256, 0, stream>>>(probs64, st, histi, q);
        scani_kernel<<<1, 64, 0, stream>>>(histi, st, q);
    }

    final_inc_kernel<<<(NNZ + 255) / 256, 256, 0, stream>>>(probs64, E, st, o_soft, o_hard, eprob_sum, hard_cnt);
    final_edge_kernel<<<(N_EDGES + 255) / 256, 256, 0, stream>>>(eprob_sum, edge_cnt, hard_cnt, o_ep, o_es, o_eh);
}